// Round 17
// baseline (103.472 us; speedup 1.0000x reference)
//
#include <hip/hip_runtime.h>

#define N_NODES 100000
#define N_EDGES 1600000
#define IN_DIM 128
#define HID_DIM 32

#define NPB 256                                   // nodes per bucket
#define BSHIFT 8
#define NBUCK ((N_NODES + NPB - 1) / NPB)         // 391
#define EPB 4096                                  // edges per phaseA block
#define NBLK_E ((N_EDGES + EPB - 1) / EPB)        // 391
#define OSTRIDE (NBUCK + 1)                       // 392
#define CAPB 4608                                 // phaseB LDS capacity (lambda=4096, +8 sigma)
#define MMROWS 128
#define NBLK_MM ((N_NODES + MMROWS - 1) / MMROWS) // 782
#define MM1 352                                   // mm blocks in kernel 1
#define MM2 (NBLK_MM - MM1)                       // mm blocks in kernel 2
#define XS_STRIDE 136   // shorts; 272 B = 17*16 B (odd granule -> conflict-free b128)

typedef __attribute__((ext_vector_type(8))) short bf16x8;
typedef __attribute__((ext_vector_type(4))) float f32x4;

__device__ __forceinline__ unsigned int pack_bf16x2(float a0, float a1) {
    unsigned int u0 = __float_as_uint(a0), u1 = __float_as_uint(a1);
    u0 = (u0 + 0x7FFFu + ((u0 >> 16) & 1u)) >> 16;   // RNE
    u1 = (u1 + 0x7FFFu + ((u1 >> 16) & 1u)) >> 16;
    return u0 | (u1 << 16);
}

__device__ __forceinline__ unsigned short bf16_of(float v) {
    unsigned int u = __float_as_uint(v);
    u = (u + 0x7FFFu + ((u >> 16) & 1u)) >> 16;
    return (unsigned short)u;
}

// inclusive block scan over 512 threads (8 waves) via shfl; 2 barriers.
__device__ __forceinline__ int scan512(int v, int* wtmp) {
    const int t = threadIdx.x, lane = t & 63, wv = t >> 6;
    int incl = v;
#pragma unroll
    for (int o = 1; o < 64; o <<= 1) {
        const int n = __shfl_up(incl, o, 64);
        if (lane >= o) incl += n;
    }
    if (lane == 63) wtmp[wv] = incl;
    __syncthreads();
    if (t < 8) {
        const int wval = wtmp[t];
        int s = wval;
#pragma unroll
        for (int o = 1; o < 8; o <<= 1) {
            const int n = __shfl_up(s, o, 64);
            if (t >= o) s += n;
        }
        wtmp[t] = s - wval;   // exclusive base for wave t
    }
    __syncthreads();
    return incl + wtmp[wv];
}

// ---------- mm128 MFMA body: 128 rows, 8 waves; writes split lo/hi half-tables ----------
__device__ __forceinline__ void mm_body(char* smem, int row0,
                                        const float* __restrict__ x,
                                        const float* __restrict__ W,
                                        unsigned int* __restrict__ hlo,
                                        unsigned int* __restrict__ hhi) {
    const int tid = threadIdx.x;
    unsigned short* xbf = (unsigned short*)smem;
    const int lane = tid & 63, w = tid >> 6;

#pragma unroll
    for (int i = 0; i < 8; ++i) {
        const int idx = tid + i * 512;          // float4 index in [0,4096)
        const int r = idx >> 5, c4 = idx & 31;
        const int grow = row0 + r;
        float4 vv = (grow < N_NODES) ? ((const float4*)x)[(size_t)grow * 32 + c4]
                                     : make_float4(0.f, 0.f, 0.f, 0.f);
        *(uint2*)&xbf[r * XS_STRIDE + c4 * 4] =
            make_uint2(pack_bf16x2(vv.x, vv.y), pack_bf16x2(vv.z, vv.w));
    }

    const int colB = lane & 15, kg = lane >> 4;
    bf16x8 bfrag[2][4];
#pragma unroll
    for (int n = 0; n < 2; ++n)
#pragma unroll
        for (int kt = 0; kt < 4; ++kt) {
            const int kbase = kt * 32 + kg * 8;
            bf16x8 f;
#pragma unroll
            for (int j = 0; j < 8; ++j)
                f[j] = (short)bf16_of(W[(size_t)(kbase + j) * HID_DIM + n * 16 + colB]);
            bfrag[n][kt] = f;
        }
    __syncthreads();

    f32x4 acc0 = {0.f, 0.f, 0.f, 0.f}, acc1 = {0.f, 0.f, 0.f, 0.f};
    const int arow = w * 16 + (lane & 15);
#pragma unroll
    for (int kt = 0; kt < 4; ++kt) {
        bf16x8 a = *(bf16x8*)&xbf[arow * XS_STRIDE + kt * 32 + kg * 8];
        acc0 = __builtin_amdgcn_mfma_f32_16x16x32_bf16(a, bfrag[0][kt], acc0, 0, 0, 0);
        acc1 = __builtin_amdgcn_mfma_f32_16x16x32_bf16(a, bfrag[1][kt], acc1, 0, 0, 0);
    }
    __syncthreads();                             // xbf reads done; alias cst

    float* cst = (float*)smem;                   // 8 waves * 576 floats
    float* cw_ = cst + w * 576;
    const int crow = (lane >> 4) * 4;
#pragma unroll
    for (int r = 0; r < 4; ++r) {
        cw_[(crow + r) * 36 + (lane & 15)] = acc0[r];
        cw_[(crow + r) * 36 + 16 + (lane & 15)] = acc1[r];
    }
    __syncthreads();
    const int r = tid >> 2, q = tid & 3;
    const int grow = row0 + r;
    if (grow < N_NODES) {
        const float* cr = cst + (r >> 4) * 576 + (r & 15) * 36 + q * 8;
        uint4 o = make_uint4(pack_bf16x2(cr[0], cr[1]), pack_bf16x2(cr[2], cr[3]),
                             pack_bf16x2(cr[4], cr[5]), pack_bf16x2(cr[6], cr[7]));
        if (q < 2) ((uint4*)hlo)[(size_t)grow * 2 + q] = o;
        else       ((uint4*)hhi)[(size_t)grow * 2 + q - 2] = o;
    }
}

// ---------- K1: phaseA linear-binning (blocks 0..390) + mm rows [0, MM1*128) ----------
// staged edge: ulin = src | (dst & 255) << 17 ; wlin = bf16 weight.
__global__ __launch_bounds__(512) void fusedA(const int* __restrict__ ei,
                                              const float* __restrict__ ew,
                                              unsigned int* __restrict__ ulin,
                                              unsigned short* __restrict__ wlin,
                                              int* __restrict__ ostart,
                                              const float* __restrict__ x,
                                              const float* __restrict__ W,
                                              unsigned int* __restrict__ hlo,
                                              unsigned int* __restrict__ hhi) {
    __shared__ __align__(16) char smem[36000];
    const int tid = threadIdx.x;

    if (blockIdx.x < NBLK_E) {
        // ================= phaseA =================
        unsigned int*   stag_u = (unsigned int*)smem;            // 16384 B
        unsigned short* stag_w = (unsigned short*)(smem + 16384); // 8192 B
        int* lh     = (int*)(smem + 24576);                      // 391 counts -> cursors
        int* lstart = (int*)(smem + 26144);                      // 392 local offsets
        int* wtmp   = (int*)(smem + 27712);                      // 8 scan partials

        for (int j = tid; j < NBUCK; j += 512) lh[j] = 0;
        __syncthreads();

        // hist pass; prefetch src + bf16(w) so the loads fly over the scan barriers
        const int e0 = blockIdx.x * EPB;
        int dstr[8];
        unsigned int srcr[8];
        unsigned short wreg[8];
#pragma unroll
        for (int u = 0; u < 8; ++u) {
            const int e = e0 + u * 512 + tid;
            if (e < N_EDGES) {
                dstr[u] = ei[N_EDGES + e];
                srcr[u] = (unsigned int)ei[e];
                wreg[u] = bf16_of(ew[e]);
                atomicAdd(&lh[dstr[u] >> BSHIFT], 1);
            } else {
                dstr[u] = -1; srcr[u] = 0; wreg[u] = 0;
            }
        }
        __syncthreads();

        const int v = (tid < NBUCK) ? lh[tid] : 0;
        const int incl = scan512(v, wtmp);
        if (tid < NBUCK) lstart[tid] = incl - v;
        if (tid == NBUCK - 1) lstart[NBUCK] = incl;
        __syncthreads();
        if (tid < NBUCK) lh[tid] = 0;   // becomes cursor
        __syncthreads();

        // scatter into bucket-sorted LDS staging (registers only, no reloads)
#pragma unroll
        for (int u = 0; u < 8; ++u) {
            const int d = dstr[u];
            if (d >= 0) {
                const int b = d >> BSHIFT;
                const int slot = atomicAdd(&lh[b], 1);
                const int p = lstart[b] + slot;
                stag_u[p] = srcr[u] | ((unsigned int)(d & (NPB - 1)) << 17);
                stag_w[p] = wreg[u];
            }
        }
        __syncthreads();

        // fully-coalesced linear write-out + offset table
        const int total = lstart[NBUCK];
        const size_t gbase = (size_t)blockIdx.x * EPB;
        for (int i = tid; i < total; i += 512) {
            ulin[gbase + i] = stag_u[i];
            wlin[gbase + i] = stag_w[i];
        }
        if (tid < OSTRIDE) ostart[blockIdx.x * OSTRIDE + tid] = lstart[tid];
    } else {
        mm_body(smem, (int)(blockIdx.x - NBLK_E) * MMROWS, x, W, hlo, hhi);
    }
}

// ---------- K2: phaseB (blocks 0..390) + mm rows [MM1*128, N) ----------
// csr entry: src (17 b) | bf16(w) low-15 (w >= 0) << 17
__global__ __launch_bounds__(512) void fusedB(const int* __restrict__ ostart,
                                              const unsigned int* __restrict__ ulin,
                                              const unsigned short* __restrict__ wlin,
                                              unsigned int* __restrict__ csr,
                                              int* __restrict__ offs,
                                              const float* __restrict__ x,
                                              const float* __restrict__ W,
                                              unsigned int* __restrict__ hlo,
                                              unsigned int* __restrict__ hhi) {
    __shared__ __align__(16) char smem[50304];
    const int t = threadIdx.x;

    if (blockIdx.x < NBUCK) {
        // ================= phaseB =================
        unsigned int*   stag_u = (unsigned int*)smem;               // 18432 B
        unsigned short* stag_w = (unsigned short*)(smem + 18432);   // 9216 B
        unsigned int*   stag2  = (unsigned int*)(smem + 27648);     // 18432 B
        int* st   = (int*)(smem + 46080);                           // 391
        int* P    = (int*)(smem + 47648);                           // 392
        int* lh   = (int*)(smem + 49216);                           // 256
        int* wtmp = (int*)(smem + 50240);                           // 8
        const int b = blockIdx.x;

        // load slice metadata; base_out = tree-reduce of st (scratch in stag2)
        int s0 = 0, len = 0;
        if (t < NBLK_E) {
            s0 = ostart[t * OSTRIDE + b];
            st[t] = s0;
            len = ostart[t * OSTRIDE + b + 1] - s0;
        }
        int* red = (int*)stag2;
        red[t] = s0;
        __syncthreads();
        for (int s = 256; s > 0; s >>= 1) {
            if (t < s) red[t] += red[t + s];
            __syncthreads();
        }
        const int base_out = red[0];
        __syncthreads();

        const int incl = scan512(len, wtmp);
        if (t < NBLK_E) P[t] = incl - len;
        if (t == NBLK_E - 1) P[NBLK_E] = incl;
        __syncthreads();
        const int cnt = min(P[NBLK_E], CAPB);

        // gather slices into LDS
        for (int i = t; i < cnt; i += 512) {
            int lo = 0, hi = NBLK_E - 1;
            while (lo < hi) {
                const int mid = (lo + hi + 1) >> 1;
                if (P[mid] <= i) lo = mid; else hi = mid - 1;
            }
            const size_t g = (size_t)lo * EPB + st[lo] + (i - P[lo]);
            stag_u[i] = ulin[g];
            stag_w[i] = wlin[g];
        }
        if (t < NPB) lh[t] = 0;
        __syncthreads();

        // node histogram
        for (int i = t; i < cnt; i += 512)
            atomicAdd(&lh[(stag_u[i] >> 17) & (NPB - 1)], 1);
        __syncthreads();

        const int v = (t < NPB) ? lh[t] : 0;
        const int incl2 = scan512(v, wtmp);
        if (t < NPB) {
            const int excl = incl2 - v;
            lh[t] = excl;                         // cursor
            const int node = (b << BSHIFT) + t;
            if (node < N_NODES) offs[node] = base_out + excl;
        }
        if (b == NBUCK - 1 && t == 0) offs[N_NODES] = base_out + cnt;
        __syncthreads();

        // sort into stag2 (node order), then coalesced csr write
        for (int i = t; i < cnt; i += 512) {
            const unsigned int u = stag_u[i];
            const int dl = (u >> 17) & (NPB - 1);
            const int pos = atomicAdd(&lh[dl], 1);
            stag2[pos] = (u & 0x1FFFF) | ((unsigned int)(stag_w[i] & 0x7FFFu) << 17);
        }
        __syncthreads();
        for (int i = t; i < cnt; i += 512) csr[base_out + i] = stag2[i];
    } else {
        mm_body(smem, (int)(blockIdx.x - NBUCK + MM1) * MMROWS, x, W, hlo, hhi);
    }
}

// ---------- gathers: 4 lanes/node, two sequential half-table passes (L2-resident) ----------

__device__ __forceinline__ void bf16fma4(float acc[4], const uint2 v, const float w) {
    acc[0] += w * __uint_as_float(v.x << 16);
    acc[1] += w * __uint_as_float(v.x & 0xFFFF0000u);
    acc[2] += w * __uint_as_float(v.y << 16);
    acc[3] += w * __uint_as_float(v.y & 0xFFFF0000u);
}

// Accumulate one channel-half (16 ch): lane ln covers ch 4ln..4ln+3 (uint2 = 8 B).
__device__ __forceinline__ void half_accum(const unsigned int* __restrict__ csr,
                                           const uint2* __restrict__ hh,
                                           int i, int end, int ln, float acc[4]) {
    for (; i + 7 < end; i += 8) {
        unsigned int e[8];
        uint2 v[8];
#pragma unroll
        for (int j = 0; j < 8; ++j) e[j] = csr[i + j];
#pragma unroll
        for (int j = 0; j < 8; ++j) v[j] = hh[(size_t)(e[j] & 0x1FFFF) * 4 + ln];
#pragma unroll
        for (int j = 0; j < 8; ++j)
            bf16fma4(acc, v[j], __uint_as_float((e[j] >> 17) << 16));
    }
    if (i + 3 < end) {
        unsigned int e[4];
        uint2 v[4];
#pragma unroll
        for (int j = 0; j < 4; ++j) e[j] = csr[i + j];
#pragma unroll
        for (int j = 0; j < 4; ++j) v[j] = hh[(size_t)(e[j] & 0x1FFFF) * 4 + ln];
#pragma unroll
        for (int j = 0; j < 4; ++j)
            bf16fma4(acc, v[j], __uint_as_float((e[j] >> 17) << 16));
        i += 4;
    }
    for (; i < end; ++i) {
        const unsigned int e = csr[i];
        bf16fma4(acc, hh[(size_t)(e & 0x1FFFF) * 4 + ln], __uint_as_float((e >> 17) << 16));
    }
}

// Layer-1 aggregate fused with W2: h2 = bf16((A h1) @ W2). 64 nodes/block.
__global__ __launch_bounds__(256) void gather_mm(const int* __restrict__ offs,
                                                 const unsigned int* __restrict__ csr,
                                                 const uint2* __restrict__ h1lo,
                                                 const uint2* __restrict__ h1hi,
                                                 const float* __restrict__ W2,
                                                 unsigned int* __restrict__ h2lo,
                                                 unsigned int* __restrict__ h2hi) {
    __shared__ float W2s[HID_DIM * HID_DIM];  // 4 KB
    __shared__ float a1s[64 * 33];            // 8.4 KB, stride-33 pad
    const int tid = threadIdx.x;
    ((float4*)W2s)[tid] = ((const float4*)W2)[tid];
    const int g = tid >> 2, ln = tid & 3;
    const int node = blockIdx.x * 64 + g;
    const int node_c = min(node, N_NODES - 1);
    const int i0 = offs[node_c], end = offs[node_c + 1];

    float aclo[4] = {0.f, 0.f, 0.f, 0.f};
    float achi[4] = {0.f, 0.f, 0.f, 0.f};
    half_accum(csr, h1lo, i0, end, ln, aclo);   // pass 1: h1_lo hot in L2
    half_accum(csr, h1hi, i0, end, ln, achi);   // pass 2: h1_hi hot in L2

    __syncthreads();                          // W2s visible
#pragma unroll
    for (int j = 0; j < 4; ++j) {
        a1s[g * 33 + 4 * ln + j]      = aclo[j];
        a1s[g * 33 + 16 + 4 * ln + j] = achi[j];
    }
    __syncthreads();

    const float* ar = a1s + g * 33;
    float s[8] = {0.f, 0.f, 0.f, 0.f, 0.f, 0.f, 0.f, 0.f};
#pragma unroll
    for (int k = 0; k < HID_DIM; ++k) {
        const float av = ar[k];
        const float* wr = W2s + k * HID_DIM + 8 * ln;
#pragma unroll
        for (int j = 0; j < 8; ++j) s[j] += av * wr[j];
    }
    if (node < N_NODES) {
        uint4 o = make_uint4(pack_bf16x2(s[0], s[1]), pack_bf16x2(s[2], s[3]),
                             pack_bf16x2(s[4], s[5]), pack_bf16x2(s[6], s[7]));
        if (ln < 2) ((uint4*)h2lo)[(size_t)node * 2 + ln] = o;
        else        ((uint4*)h2hi)[(size_t)node * 2 + ln - 2] = o;
    }
}

// Layer-2 aggregate -> fp32 output. 64 nodes/block.
__global__ __launch_bounds__(256) void gather_out(const int* __restrict__ offs,
                                                  const unsigned int* __restrict__ csr,
                                                  const uint2* __restrict__ h2lo,
                                                  const uint2* __restrict__ h2hi,
                                                  float* __restrict__ out) {
    const int tid = threadIdx.x;
    const int g = tid >> 2, ln = tid & 3;
    const int node = blockIdx.x * 64 + g;
    if (node >= N_NODES) return;
    const int i0 = offs[node], end = offs[node + 1];

    float aclo[4] = {0.f, 0.f, 0.f, 0.f};
    float achi[4] = {0.f, 0.f, 0.f, 0.f};
    half_accum(csr, h2lo, i0, end, ln, aclo);
    half_accum(csr, h2hi, i0, end, ln, achi);

    ((float4*)out)[(size_t)node * 8 + ln]     = make_float4(aclo[0], aclo[1], aclo[2], aclo[3]);
    ((float4*)out)[(size_t)node * 8 + 4 + ln] = make_float4(achi[0], achi[1], achi[2], achi[3]);
}

extern "C" void kernel_launch(void* const* d_in, const int* in_sizes, int n_in,
                              void* d_out, int out_size, void* d_ws, size_t ws_size,
                              hipStream_t stream) {
    const float* x  = (const float*)d_in[0];
    const float* W1 = (const float*)d_in[1];
    const float* W2 = (const float*)d_in[2];
    const float* ew = (const float*)d_in[3];
    const int*   ei = (const int*)d_in[4];
    float* out = (float*)d_out;

    // workspace (~30 MB of 256 MB; no aliasing, no memset needed)
    unsigned int*   ulin = (unsigned int*)d_ws;                    // E*4 = 6.4 MB
    unsigned short* wlin = (unsigned short*)(ulin + N_EDGES);      // E*2 = 3.2 MB
    unsigned int*   csr  = (unsigned int*)(wlin + N_EDGES);        // E*4 = 6.4 MB
    unsigned int*   h1lo = csr + N_EDGES;                          // N*8 uints = 3.2 MB
    unsigned int*   h1hi = h1lo + (size_t)N_NODES * 8;             // 3.2 MB
    unsigned int*   h2lo = h1hi + (size_t)N_NODES * 8;             // 3.2 MB
    unsigned int*   h2hi = h2lo + (size_t)N_NODES * 8;             // 3.2 MB
    int*  offs   = (int*)(h2hi + (size_t)N_NODES * 8);             // N+1 ints
    int*  ostart = offs + N_NODES + 1;                             // NBLK_E * OSTRIDE

    // ---- K1: phaseA (linear LDS-binned) overlapped with mm rows [0, MM1*128) ----
    fusedA<<<NBLK_E + MM1, 512, 0, stream>>>(ei, ew, ulin, wlin, ostart, x, W1,
                                             h1lo, h1hi);

    // ---- K2: phaseB (bucket CSR ordering) overlapped with mm rows [MM1*128, N) ----
    fusedB<<<NBUCK + MM2, 512, 0, stream>>>(ostart, ulin, wlin, csr, offs, x, W1,
                                            h1lo, h1hi);

    // ---- Layer 1 aggregate + fused W2: h2 = bf16((A h1)@W2) ----
    gather_mm<<<(N_NODES + 63) / 64, 256, 0, stream>>>(offs, csr,
                                                       (const uint2*)h1lo,
                                                       (const uint2*)h1hi,
                                                       W2, h2lo, h2hi);

    // ---- Layer 2 aggregate: out = A h2 ----
    gather_out<<<(N_NODES + 63) / 64, 256, 0, stream>>>(offs, csr,
                                                        (const uint2*)h2lo,
                                                        (const uint2*)h2hi, out);
}

// Round 18
// 83.573 us; speedup vs baseline: 1.2381x; 1.2381x over previous
//
#include <hip/hip_runtime.h>

#define N_NODES 100000
#define N_EDGES 1600000
#define IN_DIM 128
#define HID_DIM 32

#define NPB 256                                   // nodes per bucket
#define BSHIFT 8
#define NBUCK ((N_NODES + NPB - 1) / NPB)         // 391
#define EPB 4096                                  // edges per phaseA block
#define NBLK_E ((N_EDGES + EPB - 1) / EPB)        // 391
#define OSTRIDE (NBUCK + 1)                       // 392
#define CAPB 4608                                 // phaseB LDS capacity (lambda=4096, +8 sigma)
#define MMROWS 128
#define NBLK_MM ((N_NODES + MMROWS - 1) / MMROWS) // 782
#define MM1 352                                   // mm blocks in kernel 1
#define MM2 (NBLK_MM - MM1)                       // mm blocks in kernel 2
#define XS_STRIDE 136   // shorts; 272 B = 17*16 B (odd granule -> conflict-free b128)

typedef __attribute__((ext_vector_type(8))) short bf16x8;
typedef __attribute__((ext_vector_type(4))) float f32x4;

__device__ __forceinline__ unsigned int pack_bf16x2(float a0, float a1) {
    unsigned int u0 = __float_as_uint(a0), u1 = __float_as_uint(a1);
    u0 = (u0 + 0x7FFFu + ((u0 >> 16) & 1u)) >> 16;   // RNE
    u1 = (u1 + 0x7FFFu + ((u1 >> 16) & 1u)) >> 16;
    return u0 | (u1 << 16);
}

__device__ __forceinline__ unsigned short bf16_of(float v) {
    unsigned int u = __float_as_uint(v);
    u = (u + 0x7FFFu + ((u >> 16) & 1u)) >> 16;
    return (unsigned short)u;
}

// inclusive block scan over 512 threads (8 waves) via shfl; 2 barriers.
__device__ __forceinline__ int scan512(int v, int* wtmp) {
    const int t = threadIdx.x, lane = t & 63, wv = t >> 6;
    int incl = v;
#pragma unroll
    for (int o = 1; o < 64; o <<= 1) {
        const int n = __shfl_up(incl, o, 64);
        if (lane >= o) incl += n;
    }
    if (lane == 63) wtmp[wv] = incl;
    __syncthreads();
    if (t < 8) {
        const int wval = wtmp[t];
        int s = wval;
#pragma unroll
        for (int o = 1; o < 8; o <<= 1) {
            const int n = __shfl_up(s, o, 64);
            if (t >= o) s += n;
        }
        wtmp[t] = s - wval;   // exclusive base for wave t
    }
    __syncthreads();
    return incl + wtmp[wv];
}

// ---------- mm128 MFMA branch body: 128 rows, 8 waves, smem >= 34816 B ----------
__device__ __forceinline__ void mm_body(char* smem, int row0,
                                        const float* __restrict__ x,
                                        const float* __restrict__ W,
                                        unsigned int* __restrict__ h) {
    const int tid = threadIdx.x;
    unsigned short* xbf = (unsigned short*)smem;
    const int lane = tid & 63, w = tid >> 6;

#pragma unroll
    for (int i = 0; i < 8; ++i) {
        const int idx = tid + i * 512;          // float4 index in [0,4096)
        const int r = idx >> 5, c4 = idx & 31;
        const int grow = row0 + r;
        float4 vv = (grow < N_NODES) ? ((const float4*)x)[(size_t)grow * 32 + c4]
                                     : make_float4(0.f, 0.f, 0.f, 0.f);
        *(uint2*)&xbf[r * XS_STRIDE + c4 * 4] =
            make_uint2(pack_bf16x2(vv.x, vv.y), pack_bf16x2(vv.z, vv.w));
    }

    const int colB = lane & 15, kg = lane >> 4;
    bf16x8 bfrag[2][4];
#pragma unroll
    for (int n = 0; n < 2; ++n)
#pragma unroll
        for (int kt = 0; kt < 4; ++kt) {
            const int kbase = kt * 32 + kg * 8;
            bf16x8 f;
#pragma unroll
            for (int j = 0; j < 8; ++j)
                f[j] = (short)bf16_of(W[(size_t)(kbase + j) * HID_DIM + n * 16 + colB]);
            bfrag[n][kt] = f;
        }
    __syncthreads();

    f32x4 acc0 = {0.f, 0.f, 0.f, 0.f}, acc1 = {0.f, 0.f, 0.f, 0.f};
    const int arow = w * 16 + (lane & 15);
#pragma unroll
    for (int kt = 0; kt < 4; ++kt) {
        bf16x8 a = *(bf16x8*)&xbf[arow * XS_STRIDE + kt * 32 + kg * 8];
        acc0 = __builtin_amdgcn_mfma_f32_16x16x32_bf16(a, bfrag[0][kt], acc0, 0, 0, 0);
        acc1 = __builtin_amdgcn_mfma_f32_16x16x32_bf16(a, bfrag[1][kt], acc1, 0, 0, 0);
    }
    __syncthreads();                             // xbf reads done; alias cst

    float* cst = (float*)smem;                   // 8 waves * 576 floats
    float* cw_ = cst + w * 576;
    const int crow = (lane >> 4) * 4;
#pragma unroll
    for (int r = 0; r < 4; ++r) {
        cw_[(crow + r) * 36 + (lane & 15)] = acc0[r];
        cw_[(crow + r) * 36 + 16 + (lane & 15)] = acc1[r];
    }
    __syncthreads();
    const int r = tid >> 2, q = tid & 3;
    const int grow = row0 + r;
    if (grow < N_NODES) {
        const float* cr = cst + (r >> 4) * 576 + (r & 15) * 36 + q * 8;
        uint4 o = make_uint4(pack_bf16x2(cr[0], cr[1]), pack_bf16x2(cr[2], cr[3]),
                             pack_bf16x2(cr[4], cr[5]), pack_bf16x2(cr[6], cr[7]));
        ((uint4*)h)[(size_t)grow * 4 + q] = o;
    }
}

// ---------- K1: phaseA linear-binning (blocks 0..390) + mm rows [0, MM1*128) ----------
// staged edge: ulin = src | (dst & 255) << 17 ; wlin = bf16 weight.
__global__ __launch_bounds__(512) void fusedA(const int* __restrict__ ei,
                                              const float* __restrict__ ew,
                                              unsigned int* __restrict__ ulin,
                                              unsigned short* __restrict__ wlin,
                                              int* __restrict__ ostart,
                                              const float* __restrict__ x,
                                              const float* __restrict__ W,
                                              unsigned int* __restrict__ h) {
    __shared__ __align__(16) char smem[36000];
    const int tid = threadIdx.x;

    if (blockIdx.x < NBLK_E) {
        // ================= phaseA =================
        unsigned int*   stag_u = (unsigned int*)smem;            // 16384 B
        unsigned short* stag_w = (unsigned short*)(smem + 16384); // 8192 B
        int* lh     = (int*)(smem + 24576);                      // 391 counts -> cursors
        int* lstart = (int*)(smem + 26144);                      // 392 local offsets
        int* wtmp   = (int*)(smem + 27712);                      // 8 scan partials

        for (int j = tid; j < NBUCK; j += 512) lh[j] = 0;
        __syncthreads();

        // hist pass; prefetch src + bf16(w) so the loads fly over the scan barriers
        const int e0 = blockIdx.x * EPB;
        int dstr[8];
        unsigned int srcr[8];
        unsigned short wreg[8];
#pragma unroll
        for (int u = 0; u < 8; ++u) {
            const int e = e0 + u * 512 + tid;
            if (e < N_EDGES) {
                dstr[u] = ei[N_EDGES + e];
                srcr[u] = (unsigned int)ei[e];
                wreg[u] = bf16_of(ew[e]);
                atomicAdd(&lh[dstr[u] >> BSHIFT], 1);
            } else {
                dstr[u] = -1; srcr[u] = 0; wreg[u] = 0;
            }
        }
        __syncthreads();

        const int v = (tid < NBUCK) ? lh[tid] : 0;
        const int incl = scan512(v, wtmp);
        if (tid < NBUCK) lstart[tid] = incl - v;
        if (tid == NBUCK - 1) lstart[NBUCK] = incl;
        __syncthreads();
        if (tid < NBUCK) lh[tid] = 0;   // becomes cursor
        __syncthreads();

        // scatter into bucket-sorted LDS staging (registers only, no reloads)
#pragma unroll
        for (int u = 0; u < 8; ++u) {
            const int d = dstr[u];
            if (d >= 0) {
                const int b = d >> BSHIFT;
                const int slot = atomicAdd(&lh[b], 1);
                const int p = lstart[b] + slot;
                stag_u[p] = srcr[u] | ((unsigned int)(d & (NPB - 1)) << 17);
                stag_w[p] = wreg[u];
            }
        }
        __syncthreads();

        // fully-coalesced linear write-out + offset table
        const int total = lstart[NBUCK];
        const size_t gbase = (size_t)blockIdx.x * EPB;
        for (int i = tid; i < total; i += 512) {
            ulin[gbase + i] = stag_u[i];
            wlin[gbase + i] = stag_w[i];
        }
        if (tid < OSTRIDE) ostart[blockIdx.x * OSTRIDE + tid] = lstart[tid];
    } else {
        mm_body(smem, (int)(blockIdx.x - NBLK_E) * MMROWS, x, W, h);
    }
}

// ---------- K2: phaseB (blocks 0..390) + mm rows [MM1*128, N) ----------
// csr entry: src (17 b) | bf16(w) low-15 (w >= 0) << 17
__global__ __launch_bounds__(512) void fusedB(const int* __restrict__ ostart,
                                              const unsigned int* __restrict__ ulin,
                                              const unsigned short* __restrict__ wlin,
                                              unsigned int* __restrict__ csr,
                                              int* __restrict__ offs,
                                              const float* __restrict__ x,
                                              const float* __restrict__ W,
                                              unsigned int* __restrict__ h) {
    __shared__ __align__(16) char smem[50304];
    const int t = threadIdx.x;

    if (blockIdx.x < NBUCK) {
        // ================= phaseB =================
        unsigned int*   stag_u = (unsigned int*)smem;               // 18432 B
        unsigned short* stag_w = (unsigned short*)(smem + 18432);   // 9216 B
        unsigned int*   stag2  = (unsigned int*)(smem + 27648);     // 18432 B
        int* st   = (int*)(smem + 46080);                           // 391
        int* P    = (int*)(smem + 47648);                           // 392
        int* lh   = (int*)(smem + 49216);                           // 256
        int* wtmp = (int*)(smem + 50240);                           // 8
        const int b = blockIdx.x;

        // load slice metadata; base_out = tree-reduce of st (scratch in stag2)
        int s0 = 0, len = 0;
        if (t < NBLK_E) {
            s0 = ostart[t * OSTRIDE + b];
            st[t] = s0;
            len = ostart[t * OSTRIDE + b + 1] - s0;
        }
        int* red = (int*)stag2;
        red[t] = s0;
        __syncthreads();
        for (int s = 256; s > 0; s >>= 1) {
            if (t < s) red[t] += red[t + s];
            __syncthreads();
        }
        const int base_out = red[0];
        __syncthreads();

        const int incl = scan512(len, wtmp);
        if (t < NBLK_E) P[t] = incl - len;
        if (t == NBLK_E - 1) P[NBLK_E] = incl;
        __syncthreads();
        const int cnt = min(P[NBLK_E], CAPB);

        // gather slices into LDS
        for (int i = t; i < cnt; i += 512) {
            int lo = 0, hi = NBLK_E - 1;
            while (lo < hi) {
                const int mid = (lo + hi + 1) >> 1;
                if (P[mid] <= i) lo = mid; else hi = mid - 1;
            }
            const size_t g = (size_t)lo * EPB + st[lo] + (i - P[lo]);
            stag_u[i] = ulin[g];
            stag_w[i] = wlin[g];
        }
        if (t < NPB) lh[t] = 0;
        __syncthreads();

        // node histogram
        for (int i = t; i < cnt; i += 512)
            atomicAdd(&lh[(stag_u[i] >> 17) & (NPB - 1)], 1);
        __syncthreads();

        const int v = (t < NPB) ? lh[t] : 0;
        const int incl2 = scan512(v, wtmp);
        if (t < NPB) {
            const int excl = incl2 - v;
            lh[t] = excl;                         // cursor
            const int node = (b << BSHIFT) + t;
            if (node < N_NODES) offs[node] = base_out + excl;
        }
        if (b == NBUCK - 1 && t == 0) offs[N_NODES] = base_out + cnt;
        __syncthreads();

        // sort into stag2 (node order), then coalesced csr write
        for (int i = t; i < cnt; i += 512) {
            const unsigned int u = stag_u[i];
            const int dl = (u >> 17) & (NPB - 1);
            const int pos = atomicAdd(&lh[dl], 1);
            stag2[pos] = (u & 0x1FFFF) | ((unsigned int)(stag_w[i] & 0x7FFFu) << 17);
        }
        __syncthreads();
        for (int i = t; i < cnt; i += 512) csr[base_out + i] = stag2[i];
    } else {
        mm_body(smem, (int)(blockIdx.x - NBUCK + MM1) * MMROWS, x, W, h);
    }
}

// ---------- gathers: 4 lanes/node, uint4 (8 bf16 channels) per lane, unroll 8 ----------

__device__ __forceinline__ void bf16fma8(float acc[8], const uint4 v, const float w) {
    acc[0] += w * __uint_as_float(v.x << 16);
    acc[1] += w * __uint_as_float(v.x & 0xFFFF0000u);
    acc[2] += w * __uint_as_float(v.y << 16);
    acc[3] += w * __uint_as_float(v.y & 0xFFFF0000u);
    acc[4] += w * __uint_as_float(v.z << 16);
    acc[5] += w * __uint_as_float(v.z & 0xFFFF0000u);
    acc[6] += w * __uint_as_float(v.w << 16);
    acc[7] += w * __uint_as_float(v.w & 0xFFFF0000u);
}

__device__ __forceinline__ void edge_accum(const int* __restrict__ offs,
                                           const unsigned int* __restrict__ csr,
                                           const uint4* __restrict__ h,
                                           int node, int ln, float acc[8]) {
    int i = offs[node];
    const int end = offs[node + 1];
    for (; i + 7 < end; i += 8) {
        unsigned int e[8];
        uint4 v[8];
#pragma unroll
        for (int j = 0; j < 8; ++j) e[j] = csr[i + j];
#pragma unroll
        for (int j = 0; j < 8; ++j) v[j] = h[(size_t)(e[j] & 0x1FFFF) * 4 + ln];
#pragma unroll
        for (int j = 0; j < 8; ++j)
            bf16fma8(acc, v[j], __uint_as_float((e[j] >> 17) << 16));
    }
    if (i + 3 < end) {
        unsigned int e[4];
        uint4 v[4];
#pragma unroll
        for (int j = 0; j < 4; ++j) e[j] = csr[i + j];
#pragma unroll
        for (int j = 0; j < 4; ++j) v[j] = h[(size_t)(e[j] & 0x1FFFF) * 4 + ln];
#pragma unroll
        for (int j = 0; j < 4; ++j)
            bf16fma8(acc, v[j], __uint_as_float((e[j] >> 17) << 16));
        i += 4;
    }
    for (; i < end; ++i) {
        const unsigned int e = csr[i];
        bf16fma8(acc, h[(size_t)(e & 0x1FFFF) * 4 + ln], __uint_as_float((e >> 17) << 16));
    }
}

// Layer-1 aggregate fused with W2: h2 = bf16((A h1) @ W2). 64 nodes/block.
__global__ __launch_bounds__(256) void gather_mm(const int* __restrict__ offs,
                                                 const unsigned int* __restrict__ csr,
                                                 const uint4* __restrict__ h1,
                                                 const float* __restrict__ W2,
                                                 uint4* __restrict__ h2) {
    __shared__ float W2s[HID_DIM * HID_DIM];  // 4 KB
    __shared__ float a1s[64 * 33];            // 8.4 KB, stride-33 pad
    const int tid = threadIdx.x;
    ((float4*)W2s)[tid] = ((const float4*)W2)[tid];
    const int g = tid >> 2, ln = tid & 3;
    const int node = blockIdx.x * 64 + g;
    const int node_c = min(node, N_NODES - 1);

    float acc[8] = {0.f, 0.f, 0.f, 0.f, 0.f, 0.f, 0.f, 0.f};
    edge_accum(offs, csr, h1, node_c, ln, acc);

    __syncthreads();                          // W2s visible
#pragma unroll
    for (int j = 0; j < 8; ++j) a1s[g * 33 + 8 * ln + j] = acc[j];
    __syncthreads();

    const float* ar = a1s + g * 33;
    float s[8] = {0.f, 0.f, 0.f, 0.f, 0.f, 0.f, 0.f, 0.f};
#pragma unroll
    for (int k = 0; k < HID_DIM; ++k) {
        const float av = ar[k];
        const float* wr = W2s + k * HID_DIM + 8 * ln;
#pragma unroll
        for (int j = 0; j < 8; ++j) s[j] += av * wr[j];
    }
    if (node < N_NODES)
        h2[(size_t)node * 4 + ln] = make_uint4(pack_bf16x2(s[0], s[1]),
                                               pack_bf16x2(s[2], s[3]),
                                               pack_bf16x2(s[4], s[5]),
                                               pack_bf16x2(s[6], s[7]));
}

// Layer-2 aggregate -> fp32 output. 64 nodes/block.
__global__ __launch_bounds__(256) void gather_out(const int* __restrict__ offs,
                                                  const unsigned int* __restrict__ csr,
                                                  const uint4* __restrict__ h2,
                                                  float* __restrict__ out) {
    const int tid = threadIdx.x;
    const int g = tid >> 2, ln = tid & 3;
    const int node = blockIdx.x * 64 + g;
    if (node >= N_NODES) return;

    float acc[8] = {0.f, 0.f, 0.f, 0.f, 0.f, 0.f, 0.f, 0.f};
    edge_accum(offs, csr, h2, node, ln, acc);
    ((float4*)out)[(size_t)node * 8 + 2 * ln] = make_float4(acc[0], acc[1], acc[2], acc[3]);
    ((float4*)out)[(size_t)node * 8 + 2 * ln + 1] = make_float4(acc[4], acc[5], acc[6], acc[7]);
}

extern "C" void kernel_launch(void* const* d_in, const int* in_sizes, int n_in,
                              void* d_out, int out_size, void* d_ws, size_t ws_size,
                              hipStream_t stream) {
    const float* x  = (const float*)d_in[0];
    const float* W1 = (const float*)d_in[1];
    const float* W2 = (const float*)d_in[2];
    const float* ew = (const float*)d_in[3];
    const int*   ei = (const int*)d_in[4];
    float* out = (float*)d_out;

    // workspace (~30 MB of 256 MB; no aliasing, no memset needed)
    unsigned int*   ulin = (unsigned int*)d_ws;                    // E*4 = 6.4 MB
    unsigned short* wlin = (unsigned short*)(ulin + N_EDGES);      // E*2 = 3.2 MB
    unsigned int*   csr  = (unsigned int*)(wlin + N_EDGES);        // E*4 = 6.4 MB
    unsigned int*   h1u  = csr + N_EDGES;                          // 6.4 MB
    unsigned int*   h2u  = h1u + (size_t)N_NODES * 16;             // 6.4 MB
    int*  offs   = (int*)(h2u + (size_t)N_NODES * 16);             // N+1 ints
    int*  ostart = offs + N_NODES + 1;                             // NBLK_E * OSTRIDE

    // ---- K1: phaseA (linear LDS-binned) overlapped with mm rows [0, MM1*128) ----
    fusedA<<<NBLK_E + MM1, 512, 0, stream>>>(ei, ew, ulin, wlin, ostart, x, W1, h1u);

    // ---- K2: phaseB (bucket CSR ordering) overlapped with mm rows [MM1*128, N) ----
    fusedB<<<NBUCK + MM2, 512, 0, stream>>>(ostart, ulin, wlin, csr, offs, x, W1, h1u);

    // ---- Layer 1 aggregate + fused W2: h2 = bf16((A h1)@W2) ----
    gather_mm<<<(N_NODES + 63) / 64, 256, 0, stream>>>(offs, csr, (const uint4*)h1u,
                                                       W2, (uint4*)h2u);

    // ---- Layer 2 aggregate: out = A h2 ----
    gather_out<<<(N_NODES + 63) / 64, 256, 0, stream>>>(offs, csr, (const uint4*)h2u, out);
}